// Round 2
// baseline (18197.305 us; speedup 1.0000x reference)
//
#include <hip/hip_runtime.h>
#include <cmath>

#define NN 2048
#define TT 256
#define DD 16
#define HH 256

__device__ __forceinline__ float sigmoidf_(float x){ return 1.0f/(1.0f+expf(-x)); }

// GEMM segment: acc[g][r] += X[m0+..][k] * W[g*256 + j0 + j][k]
// X: (rows, Klen) row-major (ld=ldx). W: (1024, ldw) row-major.
// Block tile: 32 rows x (4 gates x 32 cols). 256 threads.
__device__ __forceinline__ void mm_seg(const float* __restrict__ X, int ldx,
    const float* __restrict__ W, int ldw, int Klen,
    int m0, int j0, float (&acc)[4][4],
    float (*Xs)[36], float (*Ws)[128])
{
  const int tx = threadIdx.x;
  const int xm = tx>>3, xk = (tx&7)<<1;          // X stage: 32x16, float2 per thread
  const int wr = tx>>1, wk = (tx&1)<<3;          // W stage: 128 rows x 16 k, 8 floats per thread
  const int wrow = ((wr>>5)<<8) + j0 + (wr&31);  // global W row
  const int mb = (tx>>5)<<2, j = tx&31;
  for (int kb=0; kb<Klen; kb+=16){
    float2 xv = *reinterpret_cast<const float2*>(X + (size_t)(m0+xm)*ldx + kb + xk);
    Xs[xk][xm] = xv.x; Xs[xk+1][xm] = xv.y;
    const float* wp = W + (size_t)wrow*ldw + kb + wk;
    float4 w0 = *reinterpret_cast<const float4*>(wp);
    float4 w1 = *reinterpret_cast<const float4*>(wp+4);
    Ws[wk+0][wr]=w0.x; Ws[wk+1][wr]=w0.y; Ws[wk+2][wr]=w0.z; Ws[wk+3][wr]=w0.w;
    Ws[wk+4][wr]=w1.x; Ws[wk+5][wr]=w1.y; Ws[wk+6][wr]=w1.z; Ws[wk+7][wr]=w1.w;
    __syncthreads();
    #pragma unroll
    for (int k=0;k<16;k++){
      float4 a4 = *reinterpret_cast<const float4*>(&Xs[k][mb]);
      #pragma unroll
      for (int g=0; g<4; g++){
        float w = Ws[k][(g<<5)+j];
        acc[g][0] = fmaf(a4.x, w, acc[g][0]);
        acc[g][1] = fmaf(a4.y, w, acc[g][1]);
        acc[g][2] = fmaf(a4.z, w, acc[g][2]);
        acc[g][3] = fmaf(a4.w, w, acc[g][3]);
      }
    }
    __syncthreads();
  }
}

// One LSTM timestep, fused gates + pointwise. Grid (64, 8), block 256.
__global__ __launch_bounds__(256) void lstm_step(
    const float* __restrict__ Xt, int ldx, int KX,
    const float* __restrict__ Wih, const float* __restrict__ Whh,
    const float* __restrict__ bih, const float* __restrict__ bhh,
    const float* __restrict__ hprev, int ldh,
    float* __restrict__ hout, int ldo,
    float* __restrict__ c, int first)
{
  __shared__ float Xs[16][36];
  __shared__ float Ws[16][128];
  float acc[4][4] = {};
  const int m0 = blockIdx.x<<5, j0 = blockIdx.y<<5;
  mm_seg(Xt, ldx, Wih, KX, KX, m0, j0, acc, Xs, Ws);
  if (!first) mm_seg(hprev, ldh, Whh, HH, HH, m0, j0, acc, Xs, Ws);
  const int tx = threadIdx.x;
  const int j = j0 + (tx&31);
  const int mb = m0 + ((tx>>5)<<2);
  float bi = bih[j]      + bhh[j];
  float bf = bih[HH+j]   + bhh[HH+j];
  float bg = bih[2*HH+j] + bhh[2*HH+j];
  float bo = bih[3*HH+j] + bhh[3*HH+j];
  #pragma unroll
  for (int r=0;r<4;r++){
    int m = mb + r;
    float gi = acc[0][r]+bi, gf = acc[1][r]+bf, gg = acc[2][r]+bg, go = acc[3][r]+bo;
    float cold = first ? 0.f : c[(size_t)m*HH + j];
    float cn = sigmoidf_(gf)*cold + sigmoidf_(gi)*tanhf(gg);
    float hv = sigmoidf_(go)*tanhf(cn);
    c[(size_t)m*HH + j] = cn;
    hout[(size_t)m*ldo + j] = hv;
  }
}

// C(M x N) = A(M x K) @ B(K x N), all row-major. 64x64 tile, 256 threads, 4x4/thread.
__global__ __launch_bounds__(256) void gemm_nn(
    float* __restrict__ C, const float* __restrict__ A, const float* __restrict__ B,
    int K, int lda, int ldb, int ldc, int relu)
{
  __shared__ float As[16][68];
  __shared__ float Bs[16][64];
  float acc[4][4] = {};
  const int tx = threadIdx.x;
  const int m0 = blockIdx.y<<6, n0 = blockIdx.x<<6;
  const int am = tx>>2, ak = (tx&3)<<2;
  const int bk = tx>>4, bn = (tx&15)<<2;
  const int mm = (tx>>4)<<2, nc = (tx&15)<<2;
  for (int kb=0; kb<K; kb+=16){
    float4 av = *reinterpret_cast<const float4*>(A + (size_t)(m0+am)*lda + kb + ak);
    As[ak][am]=av.x; As[ak+1][am]=av.y; As[ak+2][am]=av.z; As[ak+3][am]=av.w;
    *reinterpret_cast<float4*>(&Bs[bk][bn]) =
      *reinterpret_cast<const float4*>(B + (size_t)(kb+bk)*ldb + n0 + bn);
    __syncthreads();
    #pragma unroll
    for (int k=0;k<16;k++){
      float4 a4 = *reinterpret_cast<const float4*>(&As[k][mm]);
      float4 b4 = *reinterpret_cast<const float4*>(&Bs[k][nc]);
      acc[0][0]=fmaf(a4.x,b4.x,acc[0][0]); acc[0][1]=fmaf(a4.x,b4.y,acc[0][1]);
      acc[0][2]=fmaf(a4.x,b4.z,acc[0][2]); acc[0][3]=fmaf(a4.x,b4.w,acc[0][3]);
      acc[1][0]=fmaf(a4.y,b4.x,acc[1][0]); acc[1][1]=fmaf(a4.y,b4.y,acc[1][1]);
      acc[1][2]=fmaf(a4.y,b4.z,acc[1][2]); acc[1][3]=fmaf(a4.y,b4.w,acc[1][3]);
      acc[2][0]=fmaf(a4.z,b4.x,acc[2][0]); acc[2][1]=fmaf(a4.z,b4.y,acc[2][1]);
      acc[2][2]=fmaf(a4.z,b4.z,acc[2][2]); acc[2][3]=fmaf(a4.z,b4.w,acc[2][3]);
      acc[3][0]=fmaf(a4.w,b4.x,acc[3][0]); acc[3][1]=fmaf(a4.w,b4.y,acc[3][1]);
      acc[3][2]=fmaf(a4.w,b4.z,acc[3][2]); acc[3][3]=fmaf(a4.w,b4.w,acc[3][3]);
    }
    __syncthreads();
  }
  #pragma unroll
  for (int r=0;r<4;r++){
    float4 v = make_float4(acc[r][0],acc[r][1],acc[r][2],acc[r][3]);
    if (relu){ v.x=fmaxf(v.x,0.f); v.y=fmaxf(v.y,0.f); v.z=fmaxf(v.z,0.f); v.w=fmaxf(v.w,0.f); }
    *reinterpret_cast<float4*>(C + (size_t)(m0+mm+r)*ldc + n0 + nc) = v;
  }
}

// C(M x N) = A(M x K) @ B(N x K)^T, row-major.
__global__ __launch_bounds__(256) void gemm_nt(
    float* __restrict__ C, const float* __restrict__ A, const float* __restrict__ B,
    int K, int lda, int ldb, int ldc)
{
  __shared__ float As[16][68];
  __shared__ float Bs[16][68];
  float acc[4][4] = {};
  const int tx = threadIdx.x;
  const int m0 = blockIdx.y<<6, n0 = blockIdx.x<<6;
  const int am = tx>>2, ak = (tx&3)<<2;
  const int mm = (tx>>4)<<2, nc = (tx&15)<<2;
  for (int kb=0; kb<K; kb+=16){
    float4 av = *reinterpret_cast<const float4*>(A + (size_t)(m0+am)*lda + kb + ak);
    As[ak][am]=av.x; As[ak+1][am]=av.y; As[ak+2][am]=av.z; As[ak+3][am]=av.w;
    float4 bv = *reinterpret_cast<const float4*>(B + (size_t)(n0+am)*ldb + kb + ak);
    Bs[ak][am]=bv.x; Bs[ak+1][am]=bv.y; Bs[ak+2][am]=bv.z; Bs[ak+3][am]=bv.w;
    __syncthreads();
    #pragma unroll
    for (int k=0;k<16;k++){
      float4 a4 = *reinterpret_cast<const float4*>(&As[k][mm]);
      float4 b4 = *reinterpret_cast<const float4*>(&Bs[k][nc]);
      acc[0][0]=fmaf(a4.x,b4.x,acc[0][0]); acc[0][1]=fmaf(a4.x,b4.y,acc[0][1]);
      acc[0][2]=fmaf(a4.x,b4.z,acc[0][2]); acc[0][3]=fmaf(a4.x,b4.w,acc[0][3]);
      acc[1][0]=fmaf(a4.y,b4.x,acc[1][0]); acc[1][1]=fmaf(a4.y,b4.y,acc[1][1]);
      acc[1][2]=fmaf(a4.y,b4.z,acc[1][2]); acc[1][3]=fmaf(a4.y,b4.w,acc[1][3]);
      acc[2][0]=fmaf(a4.z,b4.x,acc[2][0]); acc[2][1]=fmaf(a4.z,b4.y,acc[2][1]);
      acc[2][2]=fmaf(a4.z,b4.z,acc[2][2]); acc[2][3]=fmaf(a4.z,b4.w,acc[2][3]);
      acc[3][0]=fmaf(a4.w,b4.x,acc[3][0]); acc[3][1]=fmaf(a4.w,b4.y,acc[3][1]);
      acc[3][2]=fmaf(a4.w,b4.z,acc[3][2]); acc[3][3]=fmaf(a4.w,b4.w,acc[3][3]);
    }
    __syncthreads();
  }
  #pragma unroll
  for (int r=0;r<4;r++){
    float4 v = make_float4(acc[r][0],acc[r][1],acc[r][2],acc[r][3]);
    *reinterpret_cast<float4*>(C + (size_t)(m0+mm+r)*ldc + n0 + nc) = v;
  }
}

// Per-row mean-center + norm. Block per row (2048), 256 threads.
__global__ __launch_bounds__(256) void rowstat(const float* __restrict__ nf,
    float* __restrict__ xc, float* __restrict__ dvec)
{
  __shared__ float red[256];
  int n = blockIdx.x, tx = threadIdx.x;
  float v = nf[(size_t)n*HH + tx];
  red[tx] = v; __syncthreads();
  for (int s=128; s>0; s>>=1){ if (tx<s) red[tx]+=red[tx+s]; __syncthreads(); }
  float mean = red[0] * (1.0f/HH);
  __syncthreads();
  float d = v - mean;
  xc[(size_t)n*HH + tx] = d;
  red[tx] = d*d; __syncthreads();
  for (int s=128; s>0; s>>=1){ if (tx<s) red[tx]+=red[tx+s]; __syncthreads(); }
  if (tx==0) dvec[n] = sqrtf(red[0]);
}

// Row sums of A=corr+I -> dinv. Block per row.
__global__ __launch_bounds__(256) void rowsum(const float* __restrict__ cov,
    const float* __restrict__ dvec, float* __restrict__ dinv)
{
  __shared__ float red[256];
  int i = blockIdx.x, tx = threadIdx.x;
  float di = dvec[i];
  float s = 0.f;
  for (int j=tx; j<NN; j+=256){
    float r = cov[(size_t)i*NN + j] / (di * dvec[j]);
    if (r != r) r = 0.f; else r = fminf(1.f, fmaxf(-1.f, r));
    s += r;
  }
  red[tx]=s; __syncthreads();
  for (int st=128; st>0; st>>=1){ if (tx<st) red[tx]+=red[tx+st]; __syncthreads(); }
  if (tx==0){
    float tot = red[0] + 1.0f;          // + eye contribution to row sum
    float p = powf(tot, -0.5f);         // neg -> NaN (matches jnp.power), 0 -> inf
    if (isinf(p)) p = 0.f;
    dinv[i] = p;
  }
}

// In-place: cov -> dinv_i * (clipclean(corr)_ij + delta_ij) * dinv_j
__global__ __launch_bounds__(256) void adjnorm(float* __restrict__ cov,
    const float* __restrict__ dvec, const float* __restrict__ dinv)
{
  size_t idx = (size_t)blockIdx.x*256 + threadIdx.x;
  int i = (int)(idx >> 11), j = (int)(idx & (NN-1));
  float r = cov[idx] / (dvec[i]*dvec[j]);
  if (r != r) r = 0.f; else r = fminf(1.f, fmaxf(-1.f, r));
  if (i==j) r += 1.f;
  cov[idx] = dinv[i]*r*dinv[j];
}

// out[n] = dot(G2[n,:], Wfc) + bfc
__global__ __launch_bounds__(128) void predk(const float* __restrict__ G2,
    const float* __restrict__ Wfc, const float* __restrict__ bfc, float* __restrict__ out)
{
  int n = blockIdx.x, tx = threadIdx.x;
  float v = G2[(size_t)n*128 + tx] * Wfc[tx];
  for (int off=32; off>0; off>>=1) v += __shfl_down(v, off);
  __shared__ float p[2];
  if ((tx&63)==0) p[tx>>6] = v;
  __syncthreads();
  if (tx==0) out[n] = p[0] + p[1] + bfc[0];
}

extern "C" void kernel_launch(void* const* d_in, const int* in_sizes, int n_in,
                              void* d_out, int out_size, void* d_ws, size_t ws_size,
                              hipStream_t stream)
{
  const float* x    = (const float*)d_in[0];
  const float* Wih0 = (const float*)d_in[1];
  const float* Whh0 = (const float*)d_in[2];
  const float* bih0 = (const float*)d_in[3];
  const float* bhh0 = (const float*)d_in[4];
  const float* Wih1 = (const float*)d_in[5];
  const float* Whh1 = (const float*)d_in[6];
  const float* bih1 = (const float*)d_in[7];
  const float* bhh1 = (const float*)d_in[8];
  const float* Wg1  = (const float*)d_in[9];
  const float* Wg2  = (const float*)d_in[10];
  const float* Wfc  = (const float*)d_in[11];
  const float* bfc  = (const float*)d_in[12];
  float* out = (float*)d_out;

  // Workspace: ~38 MB total (interleaved layers; no full h0 history).
  float* ws = (float*)d_ws;
  const size_t NH = (size_t)NN*HH;                 // 2 MB each
  float* h0a  = ws;
  float* h0b  = h0a + NH;
  float* c0   = h0b + NH;
  float* h1a  = c0  + NH;
  float* h1b  = h1a + NH;
  float* c1   = h1b + NH;
  float* xc   = c1  + NH;
  float* cov  = xc  + NH;                          // N*N = 16 MB, becomes adj in place
  float* t1   = cov + (size_t)NN*NN;
  float* G1   = t1  + NH;
  float* t2   = G1  + NH;
  float* G2   = t2  + (size_t)NN*128;
  float* dvec = G2  + (size_t)NN*128;
  float* dinv = dvec + NN;

  dim3 lgrid(NN/32, 8), lblk(256);
  // Interleaved: at step t, layer-0 produces h0_cur; layer-1 immediately
  // consumes it (stream-serialized). Ping-pong h buffers per layer.
  for (int t=0; t<TT; ++t){
    const float* Xt0 = x + (size_t)t*DD;
    const float* hp0 = (t&1) ? h0a : h0b;
    float* ho0       = (t&1) ? h0b : h0a;
    hipLaunchKernelGGL(lstm_step, lgrid, lblk, 0, stream,
        Xt0, TT*DD, DD, Wih0, Whh0, bih0, bhh0,
        hp0, HH, ho0, HH, c0, (t==0)?1:0);
    const float* hp1 = (t&1) ? h1a : h1b;
    float* ho1       = (t&1) ? h1b : h1a;
    hipLaunchKernelGGL(lstm_step, lgrid, lblk, 0, stream,
        ho0, HH, HH, Wih1, Whh1, bih1, bhh1,
        hp1, HH, ho1, HH, c1, (t==0)?1:0);
  }
  const float* nf = h1b;   // t=255 is odd -> wrote h1b

  // Adjacency
  hipLaunchKernelGGL(rowstat, dim3(NN), dim3(256), 0, stream, nf, xc, dvec);
  hipLaunchKernelGGL(gemm_nt, dim3(NN/64, NN/64), dim3(256), 0, stream,
      cov, xc, xc, HH, HH, HH, NN);
  hipLaunchKernelGGL(rowsum, dim3(NN), dim3(256), 0, stream, cov, dvec, dinv);
  hipLaunchKernelGGL(adjnorm, dim3(NN*NN/256), dim3(256), 0, stream, cov, dvec, dinv);

  // GCN
  hipLaunchKernelGGL(gemm_nn, dim3(HH/64, NN/64), dim3(256), 0, stream,
      t1, nf, Wg1, HH, HH, HH, HH, 0);                   // t1 = nf @ Wg1
  hipLaunchKernelGGL(gemm_nn, dim3(HH/64, NN/64), dim3(256), 0, stream,
      G1, cov, t1, NN, NN, HH, HH, 1);                   // G1 = relu(adj @ t1)
  hipLaunchKernelGGL(gemm_nn, dim3(128/64, NN/64), dim3(256), 0, stream,
      t2, G1, Wg2, HH, HH, 128, 128, 0);                 // t2 = G1 @ Wg2
  hipLaunchKernelGGL(gemm_nn, dim3(128/64, NN/64), dim3(256), 0, stream,
      G2, cov, t2, NN, NN, 128, 128, 0);                 // G2 = adj @ t2
  hipLaunchKernelGGL(predk, dim3(NN), dim3(128), 0, stream, G2, Wfc, bfc, out);
}

// Round 3
// 7878.036 us; speedup vs baseline: 2.3099x; 2.3099x over previous
//
#include <hip/hip_runtime.h>
#include <hip/hip_bf16.h>
#include <cmath>

#define NN 2048
#define TT 256
#define DD 16
#define HH 256

typedef __attribute__((ext_vector_type(8))) short short8;
typedef __attribute__((ext_vector_type(4))) float f32x4;

__device__ __forceinline__ float sigmoidf_(float x){ return 1.0f/(1.0f+expf(-x)); }

// async 16B/lane global->LDS. lds ptr must be wave-uniform (HW: base + lane*16).
__device__ __forceinline__ void glds16(const __hip_bfloat16* g, __hip_bfloat16* l){
  __builtin_amdgcn_global_load_lds(
      (const __attribute__((address_space(1))) void*)g,
      (__attribute__((address_space(3))) void*)l, 16, 0, 0);
}

// ---------------- weight / input packing (split bf16 hi/lo) ----------------
// P (1024 x 768): [hi | lo | hi] -- pairs with A segments [hi, hi, lo]
__global__ __launch_bounds__(256) void pack_w2(const float* __restrict__ W,
                                               __hip_bfloat16* __restrict__ P){
  int tid = blockIdx.x*256 + threadIdx.x;   // 1024*256
  int r = tid >> 8, k = tid & 255;
  float w = W[tid];
  __hip_bfloat16 h = __float2bfloat16(w);
  __hip_bfloat16 l = __float2bfloat16(w - __bfloat162float(h));
  size_t base = (size_t)r*768;
  P[base + k] = h; P[base + 256 + k] = l; P[base + 512 + k] = h;
}
// Wih0 (1024 x 16) -> (1024 x 64): [hi | hi | lo | 0]
__global__ __launch_bounds__(256) void pack_w0(const float* __restrict__ W,
                                               __hip_bfloat16* __restrict__ P){
  int tid = blockIdx.x*256 + threadIdx.x;   // 64 blocks
  int r = tid >> 4, k = tid & 15;
  float w = W[tid];
  __hip_bfloat16 h = __float2bfloat16(w);
  __hip_bfloat16 l = __float2bfloat16(w - __bfloat162float(h));
  size_t base = (size_t)r*64;
  P[base + k] = h; P[base + 16 + k] = h; P[base + 32 + k] = l;
  P[base + 48 + k] = __float2bfloat16(0.0f);
}
// x (N,T,16) -> Xp (N,T,64): [hi | lo | hi | 0]
__global__ __launch_bounds__(256) void pack_x(const float* __restrict__ x,
                                              __hip_bfloat16* __restrict__ Xp){
  int tid = blockIdx.x*256 + threadIdx.x;   // 2048 blocks: (n,t)
  const float* xr = x + (size_t)tid*16;
  __hip_bfloat16* o = Xp + (size_t)tid*64;
  for (int k=0;k<16;k++){
    float v = xr[k];
    __hip_bfloat16 h = __float2bfloat16(v);
    __hip_bfloat16 l = __float2bfloat16(v - __bfloat162float(h));
    o[k] = h; o[16+k] = l; o[32+k] = h; o[48+k] = __float2bfloat16(0.0f);
  }
}
__global__ __launch_bounds__(256) void recon_nf(const __hip_bfloat16* __restrict__ hi,
    const __hip_bfloat16* __restrict__ lo, float* __restrict__ nf){
  int tid = blockIdx.x*256 + threadIdx.x;
  nf[tid] = __bfloat162float(hi[tid]) + __bfloat162float(lo[tid]);
}

// ---------------- fused two-layer skewed LSTM step (MFMA bf16x3) ----------------
// Launch t: blocks [0,256) compute layer0 step t; blocks [256,512) layer1 step t-1.
// Block: 128 m-rows x 16 j x 4 gates. 4 waves; wave w: m-rows [w*32, w*32+32).
// LDS tiles XOR-swizzled in 16B chunks (swizzle applied at global source side so
// global_load_lds's lane-contiguous LDS write lands pre-swizzled).
__global__ __launch_bounds__(256) void lstm2_step(
    int t,
    const __hip_bfloat16* __restrict__ Xp,
    const __hip_bfloat16* __restrict__ P0ih,
    const __hip_bfloat16* __restrict__ P0hh,
    const __hip_bfloat16* __restrict__ P1ih,
    const __hip_bfloat16* __restrict__ P1hh,
    const float* __restrict__ bih0, const float* __restrict__ bhh0,
    const float* __restrict__ bih1, const float* __restrict__ bhh1,
    const __hip_bfloat16* __restrict__ h0p_hi, const __hip_bfloat16* __restrict__ h0p_lo,
    __hip_bfloat16* __restrict__ h0o_hi, __hip_bfloat16* __restrict__ h0o_lo,
    const __hip_bfloat16* __restrict__ h1p_hi, const __hip_bfloat16* __restrict__ h1p_lo,
    __hip_bfloat16* __restrict__ h1o_hi, __hip_bfloat16* __restrict__ h1o_lo,
    float* __restrict__ c0, float* __restrict__ c1)
{
  __shared__ __align__(16) __hip_bfloat16 As[128*64];
  __shared__ __align__(16) __hip_bfloat16 Bs[64*64];
  const int bid = blockIdx.x;
  const bool isL0 = bid < 256;
  if (isL0 && t >= TT) return;        // final launch: layer1 only
  if (!isL0 && t == 0) return;        // first launch: layer0 only
  const int idx = bid & 255;
  const int m0 = (idx >> 4) << 7;     // 16 m-tiles of 128
  const int j0 = (idx & 15) << 4;     // 16 j-tiles of 16

  // segment list: (A, lda, B(with col offset), ldb, K)
  const __hip_bfloat16* SA[6]; const __hip_bfloat16* SB[6];
  int slda[6], sldb[6], sK[6]; int ns = 0;
  if (isL0){
    if (t != 0){
      SA[ns]=h0p_hi; SB[ns]=P0hh;     slda[ns]=HH;    sldb[ns]=768; sK[ns]=256; ns++;
      SA[ns]=h0p_hi; SB[ns]=P0hh+256; slda[ns]=HH;    sldb[ns]=768; sK[ns]=256; ns++;
      SA[ns]=h0p_lo; SB[ns]=P0hh+512; slda[ns]=HH;    sldb[ns]=768; sK[ns]=256; ns++;
    }
    SA[ns]=Xp + (size_t)t*64; SB[ns]=P0ih; slda[ns]=TT*64; sldb[ns]=64; sK[ns]=64; ns++;
  } else {
    SA[ns]=h0p_hi; SB[ns]=P1ih;     slda[ns]=HH; sldb[ns]=768; sK[ns]=256; ns++;
    SA[ns]=h0p_hi; SB[ns]=P1ih+256; slda[ns]=HH; sldb[ns]=768; sK[ns]=256; ns++;
    SA[ns]=h0p_lo; SB[ns]=P1ih+512; slda[ns]=HH; sldb[ns]=768; sK[ns]=256; ns++;
    if (t != 1){
      SA[ns]=h1p_hi; SB[ns]=P1hh;     slda[ns]=HH; sldb[ns]=768; sK[ns]=256; ns++;
      SA[ns]=h1p_hi; SB[ns]=P1hh+256; slda[ns]=HH; sldb[ns]=768; sK[ns]=256; ns++;
      SA[ns]=h1p_lo; SB[ns]=P1hh+512; slda[ns]=HH; sldb[ns]=768; sK[ns]=256; ns++;
    }
  }

  const int lane = threadIdx.x & 63, wv = threadIdx.x >> 6;
  const int rr = lane >> 3;                       // staging row within 8-row group
  const int sw8 = (((lane & 7) ^ rr) << 3);       // source-side XOR swizzle (elements)
  f32x4 acc[2][4] = {};                           // [m-subtile][gate]
  __hip_bfloat16* Alds = &As[(wv*32)*64];
  __hip_bfloat16* Blds = &Bs[(wv*16)*64];

  for (int s=0; s<ns; ++s){
    const size_t lda = (size_t)slda[s], ldb = (size_t)sldb[s];
    // A: wave stages its 32 m-rows; B: wave wv stages gate-group wv's 16 rows
    const __hip_bfloat16* Ab = SA[s] + (size_t)(m0 + wv*32 + rr)*lda + sw8;
    const __hip_bfloat16* Bb = SB[s] + (size_t)(wv*256 + j0 + rr)*ldb + sw8;
    for (int kb=0; kb<sK[s]; kb+=64){
      #pragma unroll
      for (int c2=0;c2<4;c2++) glds16(Ab + (size_t)(c2*8)*lda + kb, Alds + c2*8*64);
      #pragma unroll
      for (int c2=0;c2<2;c2++) glds16(Bb + (size_t)(c2*8)*ldb + kb, Blds + c2*8*64);
      __syncthreads();
      #pragma unroll
      for (int w2=0; w2<2; ++w2){
        const int sl8 = ((((w2<<2) + (lane>>4)) ^ (lane&7)) << 3);
        short8 a0 = *(const short8*)&As[(wv*32 +      (lane&15))*64 + sl8];
        short8 a1 = *(const short8*)&As[(wv*32 + 16 + (lane&15))*64 + sl8];
        #pragma unroll
        for (int g=0; g<4; ++g){
          short8 b = *(const short8*)&Bs[((g<<4) + (lane&15))*64 + sl8];
          acc[0][g] = __builtin_amdgcn_mfma_f32_16x16x32_bf16(a0, b, acc[0][g], 0,0,0);
          acc[1][g] = __builtin_amdgcn_mfma_f32_16x16x32_bf16(a1, b, acc[1][g], 0,0,0);
        }
      }
      __syncthreads();
    }
  }

  // epilogue: lane holds all 4 gates for its (m, j) pairs. C map: col=lane&15, row=quad*4+r
  const int j = j0 + (lane & 15);
  const float* bih = isL0 ? bih0 : bih1;
  const float* bhh = isL0 ? bhh0 : bhh1;
  float* cst = isL0 ? c0 : c1;
  __hip_bfloat16* ohi = isL0 ? h0o_hi : h1o_hi;
  __hip_bfloat16* olo = isL0 ? h0o_lo : h1o_lo;
  const int first = isL0 ? (t==0) : (t==1);
  const float b0 = bih[j]        + bhh[j];
  const float b1 = bih[HH + j]   + bhh[HH + j];
  const float b2 = bih[2*HH + j] + bhh[2*HH + j];
  const float b3 = bih[3*HH + j] + bhh[3*HH + j];
  #pragma unroll
  for (int mt=0; mt<2; ++mt){
    const int mrb = m0 + wv*32 + mt*16 + ((lane>>4)<<2);
    #pragma unroll
    for (int r=0; r<4; ++r){
      const size_t mi = (size_t)(mrb + r)*HH + j;
      float gi = acc[mt][0][r] + b0;
      float gf = acc[mt][1][r] + b1;
      float gg = acc[mt][2][r] + b2;
      float go = acc[mt][3][r] + b3;
      float cold = first ? 0.f : cst[mi];
      float cn = sigmoidf_(gf)*cold + sigmoidf_(gi)*tanhf(gg);
      float hv = sigmoidf_(go)*tanhf(cn);
      cst[mi] = cn;
      __hip_bfloat16 hb = __float2bfloat16(hv);
      ohi[mi] = hb;
      olo[mi] = __float2bfloat16(hv - __bfloat162float(hb));
    }
  }
}

// ---------------- fp32 tail (unchanged from R2, passed) ----------------
__global__ __launch_bounds__(256) void gemm_nn(
    float* __restrict__ C, const float* __restrict__ A, const float* __restrict__ B,
    int K, int lda, int ldb, int ldc, int relu)
{
  __shared__ float As_[16][68];
  __shared__ float Bs_[16][64];
  float acc[4][4] = {};
  const int tx = threadIdx.x;
  const int m0 = blockIdx.y<<6, n0 = blockIdx.x<<6;
  const int am = tx>>2, ak = (tx&3)<<2;
  const int bk = tx>>4, bn = (tx&15)<<2;
  const int mm = (tx>>4)<<2, nc = (tx&15)<<2;
  for (int kb=0; kb<K; kb+=16){
    float4 av = *reinterpret_cast<const float4*>(A + (size_t)(m0+am)*lda + kb + ak);
    As_[ak][am]=av.x; As_[ak+1][am]=av.y; As_[ak+2][am]=av.z; As_[ak+3][am]=av.w;
    *reinterpret_cast<float4*>(&Bs_[bk][bn]) =
      *reinterpret_cast<const float4*>(B + (size_t)(kb+bk)*ldb + n0 + bn);
    __syncthreads();
    #pragma unroll
    for (int k=0;k<16;k++){
      float4 a4 = *reinterpret_cast<const float4*>(&As_[k][mm]);
      float4 b4 = *reinterpret_cast<const float4*>(&Bs_[k][nc]);
      acc[0][0]=fmaf(a4.x,b4.x,acc[0][0]); acc[0][1]=fmaf(a4.x,b4.y,acc[0][1]);
      acc[0][2]=fmaf(a4.x,b4.z,acc[0][2]); acc[0][3]=fmaf(a4.x,b4.w,acc[0][3]);
      acc[1][0]=fmaf(a4.y,b4.x,acc[1][0]); acc[1][1]=fmaf(a4.y,b4.y,acc[1][1]);
      acc[1][2]=fmaf(a4.y,b4.z,acc[1][2]); acc[1][3]=fmaf(a4.y,b4.w,acc[1][3]);
      acc[2][0]=fmaf(a4.z,b4.x,acc[2][0]); acc[2][1]=fmaf(a4.z,b4.y,acc[2][1]);
      acc[2][2]=fmaf(a4.z,b4.z,acc[2][2]); acc[2][3]=fmaf(a4.z,b4.w,acc[2][3]);
      acc[3][0]=fmaf(a4.w,b4.x,acc[3][0]); acc[3][1]=fmaf(a4.w,b4.y,acc[3][1]);
      acc[3][2]=fmaf(a4.w,b4.z,acc[3][2]); acc[3][3]=fmaf(a4.w,b4.w,acc[3][3]);
    }
    __syncthreads();
  }
  #pragma unroll
  for (int r=0;r<4;r++){
    float4 v = make_float4(acc[r][0],acc[r][1],acc[r][2],acc[r][3]);
    if (relu){ v.x=fmaxf(v.x,0.f); v.y=fmaxf(v.y,0.f); v.z=fmaxf(v.z,0.f); v.w=fmaxf(v.w,0.f); }
    *reinterpret_cast<float4*>(C + (size_t)(m0+mm+r)*ldc + n0 + nc) = v;
  }
}

__global__ __launch_bounds__(256) void gemm_nt(
    float* __restrict__ C, const float* __restrict__ A, const float* __restrict__ B,
    int K, int lda, int ldb, int ldc)
{
  __shared__ float As_[16][68];
  __shared__ float Bs_[16][68];
  float acc[4][4] = {};
  const int tx = threadIdx.x;
  const int m0 = blockIdx.y<<6, n0 = blockIdx.x<<6;
  const int am = tx>>2, ak = (tx&3)<<2;
  const int mm = (tx>>4)<<2, nc = (tx&15)<<2;
  for (int kb=0; kb<K; kb+=16){
    float4 av = *reinterpret_cast<const float4*>(A + (size_t)(m0+am)*lda + kb + ak);
    As_[ak][am]=av.x; As_[ak+1][am]=av.y; As_[ak+2][am]=av.z; As_[ak+3][am]=av.w;
    float4 bv = *reinterpret_cast<const float4*>(B + (size_t)(n0+am)*ldb + kb + ak);
    Bs_[ak][am]=bv.x; Bs_[ak+1][am]=bv.y; Bs_[ak+2][am]=bv.z; Bs_[ak+3][am]=bv.w;
    __syncthreads();
    #pragma unroll
    for (int k=0;k<16;k++){
      float4 a4 = *reinterpret_cast<const float4*>(&As_[k][mm]);
      float4 b4 = *reinterpret_cast<const float4*>(&Bs_[k][nc]);
      acc[0][0]=fmaf(a4.x,b4.x,acc[0][0]); acc[0][1]=fmaf(a4.x,b4.y,acc[0][1]);
      acc[0][2]=fmaf(a4.x,b4.z,acc[0][2]); acc[0][3]=fmaf(a4.x,b4.w,acc[0][3]);
      acc[1][0]=fmaf(a4.y,b4.x,acc[1][0]); acc[1][1]=fmaf(a4.y,b4.y,acc[1][1]);
      acc[1][2]=fmaf(a4.y,b4.z,acc[1][2]); acc[1][3]=fmaf(a4.y,b4.w,acc[1][3]);
      acc[2][0]=fmaf(a4.z,b4.x,acc[2][0]); acc[2][1]=fmaf(a4.z,b4.y,acc[2][1]);
      acc[2][2]=fmaf(a4.z,b4.z,acc[2][2]); acc[2][3]=fmaf(a4.z,b4.w,acc[2][3]);
      acc[3][0]=fmaf(a4.w,b4.x,acc[3][0]); acc[3][1]=fmaf(a4.w,b4.y,acc[3][1]);
      acc[3][2]=fmaf(a4.w,b4.z,acc[3][2]); acc[3][3]=fmaf(a4.w,b4.w,acc[3][3]);
    }
    __syncthreads();
  }
  #pragma unroll
  for (int r=0;r<4;r++){
    float4 v = make_float4(acc[r][0],acc[r][1],acc[r][2],acc[r][3]);
    *reinterpret_cast<float4*>(C + (size_t)(m0+mm+r)*ldc + n0 + nc) = v;
  }
}

__global__ __launch_bounds__(256) void rowstat(const float* __restrict__ nf,
    float* __restrict__ xc, float* __restrict__ dvec)
{
  __shared__ float red[256];
  int n = blockIdx.x, tx = threadIdx.x;
  float v = nf[(size_t)n*HH + tx];
  red[tx] = v; __syncthreads();
  for (int s=128; s>0; s>>=1){ if (tx<s) red[tx]+=red[tx+s]; __syncthreads(); }
  float mean = red[0] * (1.0f/HH);
  __syncthreads();
  float d = v - mean;
  xc[(size_t)n*HH + tx] = d;
  red[tx] = d*d; __syncthreads();
  for (int s=128; s>0; s>>=1){ if (tx<s) red[tx]+=red[tx+s]; __syncthreads(); }
  if (tx==0) dvec[n] = sqrtf(red[0]);
}

__global__ __launch_bounds__(256) void rowsum(const float* __restrict__ cov,
    const float* __restrict__ dvec, float* __restrict__ dinv)
{
  __shared__ float red[256];
  int i = blockIdx.x, tx = threadIdx.x;
  float di = dvec[i];
  float s = 0.f;
  for (int jj=tx; jj<NN; jj+=256){
    float r = cov[(size_t)i*NN + jj] / (di * dvec[jj]);
    if (r != r) r = 0.f; else r = fminf(1.f, fmaxf(-1.f, r));
    s += r;
  }
  red[tx]=s; __syncthreads();
  for (int st=128; st>0; st>>=1){ if (tx<st) red[tx]+=red[tx+st]; __syncthreads(); }
  if (tx==0){
    float tot = red[0] + 1.0f;
    float p = powf(tot, -0.5f);
    if (isinf(p)) p = 0.f;
    dinv[i] = p;
  }
}

__global__ __launch_bounds__(256) void adjnorm(float* __restrict__ cov,
    const float* __restrict__ dvec, const float* __restrict__ dinv)
{
  size_t idx = (size_t)blockIdx.x*256 + threadIdx.x;
  int i = (int)(idx >> 11), jj = (int)(idx & (NN-1));
  float r = cov[idx] / (dvec[i]*dvec[jj]);
  if (r != r) r = 0.f; else r = fminf(1.f, fmaxf(-1.f, r));
  if (i==jj) r += 1.f;
  cov[idx] = dinv[i]*r*dinv[jj];
}

__global__ __launch_bounds__(128) void predk(const float* __restrict__ G2,
    const float* __restrict__ Wfc, const float* __restrict__ bfc, float* __restrict__ out)
{
  int n = blockIdx.x, tx = threadIdx.x;
  float v = G2[(size_t)n*128 + tx] * Wfc[tx];
  for (int off=32; off>0; off>>=1) v += __shfl_down(v, off);
  __shared__ float p[2];
  if ((tx&63)==0) p[tx>>6] = v;
  __syncthreads();
  if (tx==0) out[n] = p[0] + p[1] + bfc[0];
}

extern "C" void kernel_launch(void* const* d_in, const int* in_sizes, int n_in,
                              void* d_out, int out_size, void* d_ws, size_t ws_size,
                              hipStream_t stream)
{
  const float* x    = (const float*)d_in[0];
  const float* Wih0 = (const float*)d_in[1];
  const float* Whh0 = (const float*)d_in[2];
  const float* bih0 = (const float*)d_in[3];
  const float* bhh0 = (const float*)d_in[4];
  const float* Wih1 = (const float*)d_in[5];
  const float* Whh1 = (const float*)d_in[6];
  const float* bih1 = (const float*)d_in[7];
  const float* bhh1 = (const float*)d_in[8];
  const float* Wg1  = (const float*)d_in[9];
  const float* Wg2  = (const float*)d_in[10];
  const float* Wfc  = (const float*)d_in[11];
  const float* bfc  = (const float*)d_in[12];
  float* out = (float*)d_out;

  // workspace carve (~110 MB)
  char* w = (char*)d_ws;
  auto alloc = [&](size_t bytes){ char* p = w; w += (bytes + 255) & ~(size_t)255; return p; };
  __hip_bfloat16* Xp   = (__hip_bfloat16*)alloc((size_t)NN*TT*64*2);
  __hip_bfloat16* P0hh = (__hip_bfloat16*)alloc((size_t)1024*768*2);
  __hip_bfloat16* P1ih = (__hip_bfloat16*)alloc((size_t)1024*768*2);
  __hip_bfloat16* P1hh = (__hip_bfloat16*)alloc((size_t)1024*768*2);
  __hip_bfloat16* P0ih = (__hip_bfloat16*)alloc((size_t)1024*64*2);
  __hip_bfloat16 *H0hi[2], *H0lo[2], *H1hi[2], *H1lo[2];
  for (int i=0;i<2;i++){ H0hi[i]=(__hip_bfloat16*)alloc((size_t)NN*HH*2);
                         H0lo[i]=(__hip_bfloat16*)alloc((size_t)NN*HH*2); }
  for (int i=0;i<2;i++){ H1hi[i]=(__hip_bfloat16*)alloc((size_t)NN*HH*2);
                         H1lo[i]=(__hip_bfloat16*)alloc((size_t)NN*HH*2); }
  float* c0   = (float*)alloc((size_t)NN*HH*4);
  float* c1   = (float*)alloc((size_t)NN*HH*4);
  float* nf   = (float*)alloc((size_t)NN*HH*4);
  float* xc   = (float*)alloc((size_t)NN*HH*4);
  float* cov  = (float*)alloc((size_t)NN*NN*4);
  float* t1   = (float*)alloc((size_t)NN*HH*4);
  float* G1   = (float*)alloc((size_t)NN*HH*4);
  float* t2   = (float*)alloc((size_t)NN*128*4);
  float* G2   = (float*)alloc((size_t)NN*128*4);
  float* dvec = (float*)alloc((size_t)NN*4);
  float* dinv = (float*)alloc((size_t)NN*4);

  // pack weights + inputs (once per call; graph-safe)
  hipLaunchKernelGGL(pack_w2, dim3(1024), dim3(256), 0, stream, Whh0, P0hh);
  hipLaunchKernelGGL(pack_w2, dim3(1024), dim3(256), 0, stream, Wih1, P1ih);
  hipLaunchKernelGGL(pack_w2, dim3(1024), dim3(256), 0, stream, Whh1, P1hh);
  hipLaunchKernelGGL(pack_w0, dim3(64),   dim3(256), 0, stream, Wih0, P0ih);
  hipLaunchKernelGGL(pack_x,  dim3(2048), dim3(256), 0, stream, x, Xp);

  // skewed recurrence: launch t runs L0(t) and L1(t-1)
  for (int t=0; t<=TT; ++t){
    const __hip_bfloat16 *h0p_hi = H0hi[(t+1)&1], *h0p_lo = H0lo[(t+1)&1];
    __hip_bfloat16 *h0o_hi = H0hi[t&1], *h0o_lo = H0lo[t&1];
    const __hip_bfloat16 *h1p_hi = H1hi[t&1], *h1p_lo = H1lo[t&1];
    __hip_bfloat16 *h1o_hi = H1hi[(t+1)&1], *h1o_lo = H1lo[(t+1)&1];
    hipLaunchKernelGGL(lstm2_step, dim3(512), dim3(256), 0, stream,
        t, Xp, P0ih, P0hh, P1ih, P1hh, bih0, bhh0, bih1, bhh1,
        h0p_hi, h0p_lo, h0o_hi, h0o_lo, h1p_hi, h1p_lo, h1o_hi, h1o_lo, c0, c1);
  }
  // final h1 (s=255, odd) lives in H1[1]
  hipLaunchKernelGGL(recon_nf, dim3(2048), dim3(256), 0, stream, H1hi[1], H1lo[1], nf);

  // adjacency
  hipLaunchKernelGGL(rowstat, dim3(NN), dim3(256), 0, stream, nf, xc, dvec);
  hipLaunchKernelGGL(gemm_nt, dim3(NN/64, NN/64), dim3(256), 0, stream,
      cov, xc, xc, HH, HH, HH, NN);
  hipLaunchKernelGGL(rowsum, dim3(NN), dim3(256), 0, stream, cov, dvec, dinv);
  hipLaunchKernelGGL(adjnorm, dim3(NN*NN/256), dim3(256), 0, stream, cov, dvec, dinv);

  // GCN
  hipLaunchKernelGGL(gemm_nn, dim3(HH/64, NN/64), dim3(256), 0, stream,
      t1, nf, Wg1, HH, HH, HH, HH, 0);
  hipLaunchKernelGGL(gemm_nn, dim3(HH/64, NN/64), dim3(256), 0, stream,
      G1, cov, t1, NN, NN, HH, HH, 1);
  hipLaunchKernelGGL(gemm_nn, dim3(128/64, NN/64), dim3(256), 0, stream,
      t2, G1, Wg2, HH, HH, 128, 128, 0);
  hipLaunchKernelGGL(gemm_nn, dim3(128/64, NN/64), dim3(256), 0, stream,
      G2, cov, t2, NN, NN, 128, 128, 0);
  hipLaunchKernelGGL(predk, dim3(NN), dim3(128), 0, stream, G2, Wfc, bfc, out);
}